// Round 3
// baseline (175.665 us; speedup 1.0000x reference)
//
#include <hip/hip_runtime.h>

// Problem constants (fixed by the reference):
//   T = B*C = 4 trees, N = 262144 = 2^18 nodes/tree, HW = 1048576 = 2^20 pixels/tree
#define NT 4
#define NN 262144
#define NMASK (NN - 1)
#define HW 1048576
#define KPRE 8192            // prefix region solved in LDS (64KB)
#define CNT_OFF (12 << 20)   // counters live at d_ws + 12MB (after cmb 8MB + v 4MB)

// ---------------------------------------------------------------------------
// XCD-affinity work queues. Each block reads its physical XCC id (HW-verified
// on gfx950) and claims a chunk of "its" tree (tree = xcd/2: 8 XCDs, 4 trees)
// from a per-tree atomic counter. If its tree is done it probes the others,
// so ALL chunks get claimed no matter what XCC_ID returns: #blocks == #chunks
// and a block exits unclaimed only if every counter is >= limit, which means
// all chunks were claimed. Correctness is mapping-independent; only locality
// (the per-XCD L2 working set = one tree) depends on it.
// ---------------------------------------------------------------------------
__device__ __forceinline__ int xcd_pref() {
    int x;
    asm volatile("s_getreg_b32 %0, hwreg(HW_REG_XCC_ID)" : "=s"(x));
    return (x & 7) >> 1;
}

__device__ __forceinline__ int claim_chunk(int* cnt, int limit, int pref, int* tree_out) {
    for (int d = 0; d < 4; ++d) {
        int t = (pref + d) & 3;
        int c = atomicAdd(&cnt[t * 16], 1);   // counters 64B apart (no line sharing)
        if (c < limit) { *tree_out = t; return c; }
    }
    return -1;
}

// ---------------------------------------------------------------------------
// K1: build packed node records {parent, c}:
//   c[i] = sigmoid(clip(1000*(attr[i]-thr), -12, 12)) * (levels[i]-levels[parent[i]])
//   c[root]=levels[root], parent[root]=0
// int4/float4 streams; the levels[parent] gather stays tree-local (1MB -> L2).
// ---------------------------------------------------------------------------
__global__ __launch_bounds__(256) void k_build(const float* __restrict__ attr,
                                               const float* __restrict__ levels,
                                               const float* __restrict__ thr,
                                               const int* __restrict__ parent,
                                               int2* __restrict__ cmb,
                                               int* __restrict__ cnt) {
    __shared__ int s_tree, s_chunk;
    if (threadIdx.x == 0) {
        int tr, ck = claim_chunk(cnt, 256, xcd_pref(), &tr);
        s_tree = tr; s_chunk = ck;
    }
    __syncthreads();
    if (s_chunk < 0) return;
    int tree = s_tree, tbase = tree << 18;
    int idx4 = s_chunk * 256 + threadIdx.x;        // int4-granule index in tree
    int n0 = idx4 * 4;                             // first of 4 nodes

    int4   p4 = ((const int4*)(parent + tbase))[idx4];
    float4 a4 = ((const float4*)(attr + tbase))[idx4];
    float4 l4 = ((const float4*)(levels + tbase))[idx4];
    float t0 = thr[0];

    int   pe[4] = {p4.x & NMASK, p4.y & NMASK, p4.z & NMASK, p4.w & NMASK};
    float ae[4] = {a4.x, a4.y, a4.z, a4.w};
    float le[4] = {l4.x, l4.y, l4.z, l4.w};
    int   oc[8];
#pragma unroll
    for (int e = 0; e < 4; ++e) {
        float lp = levels[tbase + pe[e]];          // tree-local random gather
        float z = 1000.0f * (ae[e] - t0);
        z = fminf(fmaxf(z, -12.0f), 12.0f);
        float s = 1.0f / (1.0f + __expf(-z));
        float c = s * (le[e] - lp);
        int p = pe[e];
        if (n0 + e == 0) { c = le[e]; p = 0; }     // root
        oc[2 * e] = p; oc[2 * e + 1] = __float_as_int(c);
    }
    int4* dst = (int4*)(cmb + tbase);
    dst[2 * idx4]     = make_int4(oc[0], oc[1], oc[2], oc[3]);
    dst[2 * idx4 + 1] = make_int4(oc[4], oc[5], oc[6], oc[7]);
}

// ---------------------------------------------------------------------------
// K2: prefix solve entirely in LDS. One block per tree loads cmb[0..KPRE)
// (64KB, coalesced), walks all KPRE chains in shared memory (8 chains/thread
// for ILP), writes v[0..KPRE). Zero global gathers.
// ---------------------------------------------------------------------------
__global__ __launch_bounds__(1024) void k_prefix(const int2* __restrict__ cmb,
                                                 float* __restrict__ v) {
    __shared__ int   ps[KPRE];   // 32KB
    __shared__ float cs[KPRE];   // 32KB
    int tree = blockIdx.x;
    const int2* ct = cmb + (tree << 18);
    for (int j = threadIdx.x; j < KPRE; j += 1024) {
        int2 r = ct[j];
        ps[j] = r.x;
        cs[j] = __int_as_float(r.y);
    }
    __syncthreads();

    int   cur[8];
    float acc[8];
    int alive = 0xFF;
#pragma unroll
    for (int k = 0; k < 8; ++k) { cur[k] = threadIdx.x + k * 1024; acc[k] = 0.0f; }
    // max depth of a random recursive tree at 8192 nodes ~ e*ln(8192) ~ 25; 64 = guard
    for (int it = 0; it < 64 && __any(alive); ++it) {
#pragma unroll
        for (int k = 0; k < 8; ++k) {
            if (alive & (1 << k)) {
                int c_ = cur[k];
                acc[k] += cs[c_];                  // includes c[0]=levels[0] at root
                if (c_ == 0) alive &= ~(1 << k);
                else cur[k] = ps[c_];
            }
        }
    }
#pragma unroll
    for (int k = 0; k < 8; ++k)
        v[(tree << 18) + threadIdx.x + k * 1024] = acc[k];
}

// ---------------------------------------------------------------------------
// K3: main walk for nodes >= KPRE. Chain descends (avg ~2.5 steps) until it
// drops below KPRE, then folds in the precomputed prefix value. 4 chains per
// thread for MLP; gathers confined to this XCD's tree (2MB cmb -> L2).
// ---------------------------------------------------------------------------
__global__ __launch_bounds__(256) void k_walk(const int2* __restrict__ cmb,
                                              float* __restrict__ v,
                                              int* __restrict__ cnt) {
    __shared__ int s_tree, s_chunk;
    if (threadIdx.x == 0) {
        int tr, ck = claim_chunk(cnt + 64, (NN - KPRE) / 1024, xcd_pref(), &tr);
        s_tree = tr; s_chunk = ck;
    }
    __syncthreads();
    if (s_chunk < 0) return;
    int tree = s_tree;
    int base = KPRE + s_chunk * 1024;
    const int2*  ct = cmb + (tree << 18);
    const float* vt = v + (tree << 18);

    int   cur[4];
    float acc[4];
    int alive = 0xF;
#pragma unroll
    for (int k = 0; k < 4; ++k) { cur[k] = base + threadIdx.x + k * 256; acc[k] = 0.0f; }

    for (int it = 0; it < 64 && __any(alive); ++it) {
#pragma unroll
        for (int k = 0; k < 4; ++k) {
            if (alive & (1 << k)) {
                int2 rec = ct[cur[k]];             // 8B gather, L2-local after 1st touch
                acc[k] += __int_as_float(rec.y);
                int nxt = rec.x;
                if (nxt < KPRE) {                  // terminate on prefix region
                    acc[k] += vt[nxt];             // 32KB region -> L1/L2 hit
                    alive &= ~(1 << k);
                } else {
                    cur[k] = nxt;
                }
            }
        }
    }
#pragma unroll
    for (int k = 0; k < 4; ++k)
        v[(tree << 18) + base + threadIdx.x + k * 256] = acc[k];   // coalesced
}

// ---------------------------------------------------------------------------
// K4: pixel gather y[t][p] = v[t][p2n[t][p]], int4/float4 vectorized,
// XCD-affine so each XCD gathers from one tree's 1MB v array (L2-resident).
// ---------------------------------------------------------------------------
__global__ __launch_bounds__(256) void k_pix(const float* __restrict__ v,
                                             const int* __restrict__ p2n,
                                             float* __restrict__ y,
                                             int* __restrict__ cnt) {
    __shared__ int s_tree, s_chunk;
    if (threadIdx.x == 0) {
        int tr, ck = claim_chunk(cnt + 128, HW / 1024, xcd_pref(), &tr);
        s_tree = tr; s_chunk = ck;
    }
    __syncthreads();
    if (s_chunk < 0) return;
    int tree = s_tree;
    int i4 = (tree << 18) + s_chunk * 256 + threadIdx.x;   // int4 index (HW/4 = 2^18 per tree)
    int4 idx = ((const int4*)p2n)[i4];
    const float* vt = v + (tree << 18);
    float4 o;
    o.x = vt[idx.x & NMASK];
    o.y = vt[idx.y & NMASK];
    o.z = vt[idx.z & NMASK];
    o.w = vt[idx.w & NMASK];
    ((float4*)y)[i4] = o;
}

extern "C" void kernel_launch(void* const* d_in, const int* in_sizes, int n_in,
                              void* d_out, int out_size, void* d_ws, size_t ws_size,
                              hipStream_t stream) {
    // inputs: 0:x (unused), 1:attr_norm, 2:levels, 3:thr, 4:parent, 5:pixel_to_node
    const float* attr   = (const float*)d_in[1];
    const float* levels = (const float*)d_in[2];
    const float* thr    = (const float*)d_in[3];
    const int*   parent = (const int*)d_in[4];
    const int*   p2n    = (const int*)d_in[5];
    float*       y      = (float*)d_out;

    int2*  cmb = (int2*)d_ws;                                  // 8 MB
    float* v   = (float*)((char*)d_ws + (size_t)NT * NN * 8);  // 4 MB
    int*   cnt = (int*)((char*)d_ws + CNT_OFF);                // 3 sets x 64 ints

    hipMemsetAsync(cnt, 0, 192 * sizeof(int), stream);         // zero work-queue counters

    k_build <<<NT * NN / 1024, 256, 0, stream>>>(attr, levels, thr, parent, cmb, cnt);
    k_prefix<<<NT, 1024, 0, stream>>>(cmb, v);
    k_walk  <<<NT * (NN - KPRE) / 1024, 256, 0, stream>>>(cmb, v, cnt);
    k_pix   <<<NT * HW / 1024, 256, 0, stream>>>(v, p2n, y, cnt);
}

// Round 4
// 141.977 us; speedup vs baseline: 1.2373x; 1.2373x over previous
//
#include <hip/hip_runtime.h>

// Problem constants (fixed by the reference):
//   T = B*C = 4 trees, N = 262144 = 2^18 nodes/tree, HW = 1048576 = 2^20 pixels/tree
#define NT 4
#define NN 262144
#define NMASK (NN - 1)
#define HW 1048576
#define KPRE 8192    // prefix region: solved in-LDS by fat build blocks

// XCD-locality swizzle (perf heuristic only): blocks dispatch round-robin
// across 8 XCDs, so tree=(b&7)>>1 keeps each XCD on one tree's arrays
// (2MB cmb + 1MB v < 4MB L2).
#define SWIZ(b, tree, chunk)                \
    int tree  = ((b) & 7) >> 1;             \
    int chunk = (((b) >> 3) << 1) | ((b) & 1);

// ---------------------------------------------------------------------------
// K1: build + prefix, one launch.
//  - blocks 0..31 ("fat", 8 per tree): load levels/parent of nodes [0,KPRE)
//    into LDS, compute c locally, walk 1024 chains each fully in LDS, write
//    v[0..KPRE). No global gathers beyond the coalesced 80KB staging.
//  - blocks 32.. : normal build for nodes [KPRE, NN):
//      c[i] = sigmoid(clip(1000*(attr[i]-thr),-12,12)) * (levels[i]-levels[parent[i]])
//    packed as cmb[i] = {parent, c} so each walk step is one 8B gather.
//    cmb[0..KPRE) is never written and never read.
// ---------------------------------------------------------------------------
__global__ __launch_bounds__(256) void k_build(const float* __restrict__ attr,
                                               const float* __restrict__ levels,
                                               const float* __restrict__ thr,
                                               const int* __restrict__ parent,
                                               int2* __restrict__ cmb,
                                               float* __restrict__ v) {
    __shared__ float lvcs[KPRE];             // 32KB: levels, then overwritten with c
    __shared__ unsigned short ps[KPRE];      // 16KB: parent (always < KPRE here)

    int b = blockIdx.x;
    if (b < 32) {
        // ---- fat block: tree = (b&7)>>1, sub-block = ((b>>3)<<1)|(b&1) in [0,8)
        int tree = (b & 7) >> 1;
        int sub  = ((b >> 3) << 1) | (b & 1);
        int tbase = tree << 18;
        float t0 = thr[0];

        // stage levels + parent for [0, KPRE) (coalesced)
        for (int j = threadIdx.x; j < KPRE; j += 256) {
            lvcs[j] = levels[tbase + j];
            ps[j] = (unsigned short)(parent[tbase + j] & (KPRE - 1));
        }
        __syncthreads();

        // compute c for ALL KPRE nodes (32/thread) into registers
        float creg[32];
#pragma unroll
        for (int k = 0; k < 32; ++k) {
            int j = threadIdx.x + k * 256;
            float lv = lvcs[j];
            float lp = lvcs[ps[j]];
            float z = 1000.0f * (attr[tbase + j] - t0);
            z = fminf(fmaxf(z, -12.0f), 12.0f);
            float s = 1.0f / (1.0f + __expf(-z));
            creg[k] = (j == 0) ? lv : s * (lv - lp);
        }
        __syncthreads();
        // overwrite levels with c
#pragma unroll
        for (int k = 0; k < 32; ++k) lvcs[threadIdx.x + k * 256] = creg[k];
        __syncthreads();

        // walk this sub-block's 1024 chains entirely in LDS (4/thread)
        int   cur[4];
        float acc[4];
        int alive = 0xF;
#pragma unroll
        for (int k = 0; k < 4; ++k) { cur[k] = sub * 1024 + threadIdx.x + k * 256; acc[k] = 0.0f; }
        // max depth of random recursive tree @8192 ~ e*ln(8192) ~ 25; 64 = hang-guard
        for (int it = 0; it < 64 && __any(alive); ++it) {
#pragma unroll
            for (int k = 0; k < 4; ++k) {
                if (alive & (1 << k)) {
                    int c_ = cur[k];
                    acc[k] += lvcs[c_];              // c[0] = levels[0] at root
                    if (c_ == 0) alive &= ~(1 << k);
                    else cur[k] = ps[c_];
                }
            }
        }
#pragma unroll
        for (int k = 0; k < 4; ++k)
            v[tbase + sub * 1024 + threadIdx.x + k * 256] = acc[k];
        return;
    }

    // ---- normal build block: nodes [KPRE, NN), int4/float4 vectorized
    int g = b - 32;
    SWIZ(g, tree, chunk0)
    int chunk = 8 + chunk0;                  // chunks 8..1023 -> nodes 8192..262143
    int tbase = tree << 18;
    int idx4 = chunk * 256 + threadIdx.x;    // int4-granule index in tree
    int4   p4 = ((const int4*)(parent + tbase))[idx4];
    float4 a4 = ((const float4*)(attr + tbase))[idx4];
    float4 l4 = ((const float4*)(levels + tbase))[idx4];
    float t0 = thr[0];

    int   pe[4] = {p4.x & NMASK, p4.y & NMASK, p4.z & NMASK, p4.w & NMASK};
    float ae[4] = {a4.x, a4.y, a4.z, a4.w};
    float le[4] = {l4.x, l4.y, l4.z, l4.w};
    int   oc[8];
#pragma unroll
    for (int e = 0; e < 4; ++e) {
        float lp = levels[tbase + pe[e]];    // tree-local random gather (1MB -> L2)
        float z = 1000.0f * (ae[e] - t0);
        z = fminf(fmaxf(z, -12.0f), 12.0f);
        float s = 1.0f / (1.0f + __expf(-z));
        oc[2 * e] = pe[e];
        oc[2 * e + 1] = __float_as_int(s * (le[e] - lp));
    }
    int4* dst = (int4*)(cmb + tbase);
    dst[2 * idx4]     = make_int4(oc[0], oc[1], oc[2], oc[3]);
    dst[2 * idx4 + 1] = make_int4(oc[4], oc[5], oc[6], oc[7]);
}

// ---------------------------------------------------------------------------
// K2: main walk for nodes >= KPRE. Chain descends (avg ~2.5 steps) until it
// drops below KPRE, then folds in the precomputed prefix value (32KB/tree of
// v -> L2-hot). 4 chains/thread for memory-level parallelism.
// ---------------------------------------------------------------------------
__global__ __launch_bounds__(256) void k_walk(const int2* __restrict__ cmb,
                                              float* __restrict__ v) {
    SWIZ(blockIdx.x, tree, chunk)            // 992 blocks = 8 * 124
    int base = KPRE + chunk * 1024;
    const int2*  ct = cmb + (tree << 18);
    const float* vt = v + (tree << 18);

    int   cur[4];
    float acc[4];
    int alive = 0xF;
#pragma unroll
    for (int k = 0; k < 4; ++k) { cur[k] = base + threadIdx.x + k * 256; acc[k] = 0.0f; }

    for (int it = 0; it < 64 && __any(alive); ++it) {
#pragma unroll
        for (int k = 0; k < 4; ++k) {
            if (alive & (1 << k)) {
                int2 rec = ct[cur[k]];       // one 8B gather per step, tree-local
                acc[k] += __int_as_float(rec.y);
                int nxt = rec.x;
                if (nxt < KPRE) {            // terminate: fold in prefix value
                    acc[k] += vt[nxt];
                    alive &= ~(1 << k);
                } else {
                    cur[k] = nxt;
                }
            }
        }
    }
#pragma unroll
    for (int k = 0; k < 4; ++k)
        v[(tree << 18) + base + threadIdx.x + k * 256] = acc[k];  // coalesced
}

// ---------------------------------------------------------------------------
// K3: pixel gather  y[t][p] = v[t][p2n[t][p]], int4/float4 vectorized,
// swizzled so each XCD gathers from one tree's 1MB v array.
// ---------------------------------------------------------------------------
__global__ __launch_bounds__(256) void k_pix(const float* __restrict__ v,
                                             const int* __restrict__ p2n,
                                             float* __restrict__ y) {
    SWIZ(blockIdx.x, tree, chunk)            // 4096 blocks, 1024 chunks/tree
    int i4 = (tree << 18) + chunk * 256 + threadIdx.x;   // int4 index
    int4 idx = ((const int4*)p2n)[i4];
    const float* vt = v + (tree << 18);
    float4 o;
    o.x = vt[idx.x & NMASK];
    o.y = vt[idx.y & NMASK];
    o.z = vt[idx.z & NMASK];
    o.w = vt[idx.w & NMASK];
    ((float4*)y)[i4] = o;
}

extern "C" void kernel_launch(void* const* d_in, const int* in_sizes, int n_in,
                              void* d_out, int out_size, void* d_ws, size_t ws_size,
                              hipStream_t stream) {
    // inputs: 0:x (unused), 1:attr_norm, 2:levels, 3:thr, 4:parent, 5:pixel_to_node
    const float* attr   = (const float*)d_in[1];
    const float* levels = (const float*)d_in[2];
    const float* thr    = (const float*)d_in[3];
    const int*   parent = (const int*)d_in[4];
    const int*   p2n    = (const int*)d_in[5];
    float*       y      = (float*)d_out;

    int2*  cmb = (int2*)d_ws;                                  // 8 MB
    float* v   = (float*)((char*)d_ws + (size_t)NT * NN * 8);  // 4 MB

    // K1: 32 fat (prefix) + 4*1016 normal build blocks
    k_build<<<32 + NT * (NN - KPRE) / 1024, 256, 0, stream>>>(attr, levels, thr, parent, cmb, v);
    k_walk <<<NT * (NN - KPRE) / 1024, 256, 0, stream>>>(cmb, v);
    k_pix  <<<NT * HW / 1024, 256, 0, stream>>>(v, p2n, y);
}